// Round 6
// baseline (94.077 us; speedup 1.0000x reference)
//
#include <hip/hip_runtime.h>

#define DIM    64      // CELL_DIM
#define NCELLS 512
#define ROWS_PER_BLOCK 32
#define NROWS  8192
#define NBLOCKS (NROWS / ROWS_PER_BLOCK)   // 256 = one block per CU
#define REP    2
// R6 DIAGNOSTIC ROUND (deliberate): identical to R4 but the compute body runs
// REP=2 times per dispatch. Purpose: (a) the kernel dispatch (~65 us) rises
// above the ~41 us poison fills and surfaces in rocprof top-5 WITH counters
// (VALUBusy / Occupancy / SQ_LDS_BANK_CONFLICT / FETCH), which five rounds of
// structural changes never produced; (b) dur_us - 79.0 measures the compute
// body directly, testing the "overhead = 47 us" calibration from R2.
// asm-sinks keep rep-0 results live (rule #17: skip-ablation DCE). Output is
// written once, from the final rep -> bit-identical to R4.
__global__ __launch_bounds__(1024, 4)
void placecells_kernel(const float* __restrict__ x,
                       const float* __restrict__ pc,
                       float* __restrict__ out)
{
    extern __shared__ float pcT[];   // [64 k][512 cells] = 128 KB, quad-swizzled

    const int tid = (int)threadIdx.x;
    const int l   = tid & 63;
    const int w   = __builtin_amdgcn_readfirstlane(tid >> 6);
    const int rowBase = (int)blockIdx.x * ROWS_PER_BLOCK + w * 2;

    float4 a0A{0,0,0,0}, a0B{0,0,0,0};
    float4 a1A{0,0,0,0}, a1B{0,0,0,0};

    #pragma unroll 1
    for (int rep = 0; rep < REP; ++rep) {
        a0A = float4{0,0,0,0}; a0B = float4{0,0,0,0};
        a1A = float4{0,0,0,0}; a1B = float4{0,0,0,0};

        // ---- stage ALL of pc: global [cell][k] -> LDS pcT[k][cell] ----
        #pragma unroll
        for (int it = 0; it < 8; ++it) {
            int idx = it * 1024 + tid;        // 0..8191
            int cl  = idx >> 4;               // cell, 0..511
            int kq  = idx & 15;               // k-quad, 0..15
            float4 v = *(const float4*)(pc + cl * DIM + kq * 4);
            int pq = (cl >> 2) ^ kq;          // swizzle 16B quads within k-row
            float* p = &pcT[(kq * 4) * NCELLS + pq * 4 + (cl & 3)];
            p[0 * NCELLS] = v.x;
            p[1 * NCELLS] = v.y;
            p[2 * NCELLS] = v.z;
            p[3 * NCELLS] = v.w;
        }
        __syncthreads();

        // ---- K loop: per j, 2 conflict-free ds_read_b128 feed 32 VALU ----
        #pragma unroll 4
        for (int k4 = 0; k4 < 16; ++k4) {
            float4 xv0 = *(const float4*)(x + (rowBase + 0) * DIM + k4 * 4);
            float4 xv1 = *(const float4*)(x + (rowBase + 1) * DIM + k4 * 4);
            const int pqA = (l ^ k4) * 4;     // undo swizzle: logical quad = l
            #pragma unroll
            for (int j = 0; j < 4; ++j) {
                const float* rowp = &pcT[(k4 * 4 + j) * NCELLS];
                float4 pvA = *(const float4*)(rowp + pqA);        // cells 4l..4l+3
                float4 pvB = *(const float4*)(rowp + pqA + 256);  // cells 256+4l..+3
                float x0 = (j == 0) ? xv0.x : (j == 1) ? xv0.y : (j == 2) ? xv0.z : xv0.w;
                float x1 = (j == 0) ? xv1.x : (j == 1) ? xv1.y : (j == 2) ? xv1.z : xv1.w;
                a0A.x += fabsf(x0 - pvA.x); a0A.y += fabsf(x0 - pvA.y);
                a0A.z += fabsf(x0 - pvA.z); a0A.w += fabsf(x0 - pvA.w);
                a0B.x += fabsf(x0 - pvB.x); a0B.y += fabsf(x0 - pvB.y);
                a0B.z += fabsf(x0 - pvB.z); a0B.w += fabsf(x0 - pvB.w);
                a1A.x += fabsf(x1 - pvA.x); a1A.y += fabsf(x1 - pvA.y);
                a1A.z += fabsf(x1 - pvA.z); a1A.w += fabsf(x1 - pvA.w);
                a1B.x += fabsf(x1 - pvB.x); a1B.y += fabsf(x1 - pvB.y);
                a1B.z += fabsf(x1 - pvB.z); a1B.w += fabsf(x1 - pvB.w);
            }
        }
        __syncthreads();   // pcT rewritten by next rep

        // Keep this rep's results live so the compiler cannot DCE rep 0
        // (rule #17). Compiles to zero instructions.
        asm volatile("" :: "v"(a0A.x), "v"(a0A.y), "v"(a0A.z), "v"(a0A.w),
                           "v"(a0B.x), "v"(a0B.y), "v"(a0B.z), "v"(a0B.w),
                           "v"(a1A.x), "v"(a1A.y), "v"(a1A.z), "v"(a1A.w),
                           "v"(a1B.x), "v"(a1B.y), "v"(a1B.z), "v"(a1B.w));
    }

    // ---- softmax per row over 512 cells (one wave holds a whole row) ----
    auto finish_row = [&](float4 a, float4 b, int r) {
        float mn = fminf(fminf(fminf(a.x, a.y), fminf(a.z, a.w)),
                         fminf(fminf(b.x, b.y), fminf(b.z, b.w)));
        #pragma unroll
        for (int off = 32; off > 0; off >>= 1)
            mn = fminf(mn, __shfl_xor(mn, off, 64));
        float m2 = mn * mn;

        float e0 = __expf(0.5f * (m2 - a.x * a.x));
        float e1 = __expf(0.5f * (m2 - a.y * a.y));
        float e2 = __expf(0.5f * (m2 - a.z * a.z));
        float e3 = __expf(0.5f * (m2 - a.w * a.w));
        float e4 = __expf(0.5f * (m2 - b.x * b.x));
        float e5 = __expf(0.5f * (m2 - b.y * b.y));
        float e6 = __expf(0.5f * (m2 - b.z * b.z));
        float e7 = __expf(0.5f * (m2 - b.w * b.w));
        float s = ((e0 + e1) + (e2 + e3)) + ((e4 + e5) + (e6 + e7));
        #pragma unroll
        for (int off = 32; off > 0; off >>= 1)
            s += __shfl_xor(s, off, 64);
        float inv = 1.0f / s;

        float* orow = out + (size_t)(rowBase + r) * NCELLS;
        *(float4*)(orow + 4 * l)       = make_float4(e0 * inv, e1 * inv, e2 * inv, e3 * inv);
        *(float4*)(orow + 256 + 4 * l) = make_float4(e4 * inv, e5 * inv, e6 * inv, e7 * inv);
    };
    finish_row(a0A, a0B, 0);
    finish_row(a1A, a1B, 1);
}

extern "C" void kernel_launch(void* const* d_in, const int* in_sizes, int n_in,
                              void* d_out, int out_size, void* d_ws, size_t ws_size,
                              hipStream_t stream)
{
    const float* x  = (const float*)d_in[0];   // (8192, 64) fp32
    const float* pc = (const float*)d_in[1];   // (512, 64) fp32
    float* out = (float*)d_out;                // (8192, 512) fp32
    placecells_kernel<<<dim3(NBLOCKS), dim3(1024), DIM * NCELLS * sizeof(float), stream>>>(x, pc, out);
}

// Round 7
// 71.982 us; speedup vs baseline: 1.3069x; 1.3069x over previous
//
#include <hip/hip_runtime.h>

#define DIM    64      // CELL_DIM
#define NCELLS 512
#define ROWS_PER_BLOCK 32
#define NROWS  8192
#define NBLOCKS (NROWS / ROWS_PER_BLOCK)   // 256 = one block per CU
#define PCT_FLOATS (DIM * NCELLS)                  // 32768 fp32 = 128 KB
#define XT_FLOATS  (ROWS_PER_BLOCK * DIM)          // 2048 fp32 = 8 KB
#define LDS_BYTES  ((PCT_FLOATS + XT_FLOATS) * 4)  // 136 KB <= 160 KB/CU

// R7: stall removal on the R4 geometry (R6 diagnostic: body VALUBusy 62%,
// instrs only ~1.2x ideal, bank conflicts a 3% tax -> the 38% stall and the
// 14.4 us fixed tail are the targets).
//  - x staged to LDS: K-loop x reads are uniform-address ds_read_b128
//    (broadcast, conflict-free, offset-immediate) -> ZERO VMEM in K-loop.
//  - k4 loop fully unrolled -> deep lgkmcnt pipelining of all ds_reads.
//  - staging issues all 8 global loads before any ds_write (one vmcnt batch).
//  - tail: both rows' shfl reduction chains interleaved (independent chains
//    hide each other's latency; per-row arithmetic order unchanged).
// Geometry: 1024 thr = 16 waves, 1 block/CU, 2 rows/wave, ONE barrier.
__global__ __launch_bounds__(1024, 4)
void placecells_kernel(const float* __restrict__ x,
                       const float* __restrict__ pc,
                       float* __restrict__ out)
{
    extern __shared__ float lds[];
    float* pcT = lds;                 // [64 k][512 cells], quad-swizzled
    float* xT  = lds + PCT_FLOATS;    // [32 rows][64 k], row-major

    const int tid = (int)threadIdx.x;
    const int l   = tid & 63;
    const int w   = __builtin_amdgcn_readfirstlane(tid >> 6);
    const int rowBase = (int)blockIdx.x * ROWS_PER_BLOCK + w * 2;

    // ---- stage x slice (8 KB): 2048 floats over 1024 threads, coalesced ----
    {
        float2 v = *(const float2*)(x + (size_t)blockIdx.x * ROWS_PER_BLOCK * DIM + 2 * tid);
        *(float2*)(&xT[2 * tid]) = v;
    }

    // ---- stage pc (128 KB): 8 loads issued first, then transpose-writes ----
    auto pc_ld = [&](int i) -> float4 {          // i compile-time at call sites
        int idx = i * 1024 + tid;                // 0..8191
        int cl  = idx >> 4;                      // cell, 0..511
        int kq  = idx & 15;                      // k-quad, 0..15
        return *(const float4*)(pc + cl * DIM + kq * 4);
    };
    auto pc_st = [&](int i, float4 v) {
        int idx = i * 1024 + tid;
        int cl  = idx >> 4;
        int kq  = idx & 15;
        int pq  = (cl >> 2) ^ kq;                // quad swizzle (write spread)
        float* p = &pcT[(kq * 4) * NCELLS + pq * 4 + (cl & 3)];
        p[0 * NCELLS] = v.x;
        p[1 * NCELLS] = v.y;
        p[2 * NCELLS] = v.z;
        p[3 * NCELLS] = v.w;
    };
    float4 s0 = pc_ld(0), s1 = pc_ld(1), s2 = pc_ld(2), s3 = pc_ld(3);
    float4 s4 = pc_ld(4), s5 = pc_ld(5), s6 = pc_ld(6), s7 = pc_ld(7);
    pc_st(0, s0); pc_st(1, s1); pc_st(2, s2); pc_st(3, s3);
    pc_st(4, s4); pc_st(5, s5); pc_st(6, s6); pc_st(7, s7);

    __syncthreads();   // the ONLY barrier in the kernel

    // a{row}{chunk}: 16 accumulator VGPRs (named, R2 lesson)
    float4 a0A{0,0,0,0}, a0B{0,0,0,0};
    float4 a1A{0,0,0,0}, a1B{0,0,0,0};

    // hoisted wave-uniform x row bases: all x reads become ds_read with
    // compile-time offset immediates off these two addresses
    const float* xr0 = &xT[(w * 2 + 0) * DIM];
    const float* xr1 = &xT[(w * 2 + 1) * DIM];

    // ---- K loop: fully unrolled; per j, 2 conflict-free ds_read_b128 ----
    #pragma unroll
    for (int k4 = 0; k4 < 16; ++k4) {
        float4 xv0 = *(const float4*)(xr0 + k4 * 4);   // uniform -> broadcast
        float4 xv1 = *(const float4*)(xr1 + k4 * 4);
        const int pqA = (l ^ k4) * 4;     // undo swizzle: logical quad = l
        #pragma unroll
        for (int j = 0; j < 4; ++j) {
            const float* rowp = &pcT[(k4 * 4 + j) * NCELLS];
            float4 pvA = *(const float4*)(rowp + pqA);        // cells 4l..4l+3
            float4 pvB = *(const float4*)(rowp + pqA + 256);  // cells 256+4l..+3
            float x0 = (j == 0) ? xv0.x : (j == 1) ? xv0.y : (j == 2) ? xv0.z : xv0.w;
            float x1 = (j == 0) ? xv1.x : (j == 1) ? xv1.y : (j == 2) ? xv1.z : xv1.w;
            a0A.x += fabsf(x0 - pvA.x); a0A.y += fabsf(x0 - pvA.y);
            a0A.z += fabsf(x0 - pvA.z); a0A.w += fabsf(x0 - pvA.w);
            a0B.x += fabsf(x0 - pvB.x); a0B.y += fabsf(x0 - pvB.y);
            a0B.z += fabsf(x0 - pvB.z); a0B.w += fabsf(x0 - pvB.w);
            a1A.x += fabsf(x1 - pvA.x); a1A.y += fabsf(x1 - pvA.y);
            a1A.z += fabsf(x1 - pvA.z); a1A.w += fabsf(x1 - pvA.w);
            a1B.x += fabsf(x1 - pvB.x); a1B.y += fabsf(x1 - pvB.y);
            a1B.z += fabsf(x1 - pvB.z); a1B.w += fabsf(x1 - pvB.w);
        }
    }

    // ---- softmax tail: both rows interleaved (independent dep chains) ----
    {
        float mn0 = fminf(fminf(fminf(a0A.x, a0A.y), fminf(a0A.z, a0A.w)),
                          fminf(fminf(a0B.x, a0B.y), fminf(a0B.z, a0B.w)));
        float mn1 = fminf(fminf(fminf(a1A.x, a1A.y), fminf(a1A.z, a1A.w)),
                          fminf(fminf(a1B.x, a1B.y), fminf(a1B.z, a1B.w)));
        #pragma unroll
        for (int off = 32; off > 0; off >>= 1) {
            mn0 = fminf(mn0, __shfl_xor(mn0, off, 64));
            mn1 = fminf(mn1, __shfl_xor(mn1, off, 64));
        }
        float m20 = mn0 * mn0;
        float m21 = mn1 * mn1;

        float e00 = __expf(0.5f * (m20 - a0A.x * a0A.x));
        float e01 = __expf(0.5f * (m20 - a0A.y * a0A.y));
        float e02 = __expf(0.5f * (m20 - a0A.z * a0A.z));
        float e03 = __expf(0.5f * (m20 - a0A.w * a0A.w));
        float e04 = __expf(0.5f * (m20 - a0B.x * a0B.x));
        float e05 = __expf(0.5f * (m20 - a0B.y * a0B.y));
        float e06 = __expf(0.5f * (m20 - a0B.z * a0B.z));
        float e07 = __expf(0.5f * (m20 - a0B.w * a0B.w));
        float e10 = __expf(0.5f * (m21 - a1A.x * a1A.x));
        float e11 = __expf(0.5f * (m21 - a1A.y * a1A.y));
        float e12 = __expf(0.5f * (m21 - a1A.z * a1A.z));
        float e13 = __expf(0.5f * (m21 - a1A.w * a1A.w));
        float e14 = __expf(0.5f * (m21 - a1B.x * a1B.x));
        float e15 = __expf(0.5f * (m21 - a1B.y * a1B.y));
        float e16 = __expf(0.5f * (m21 - a1B.z * a1B.z));
        float e17 = __expf(0.5f * (m21 - a1B.w * a1B.w));

        float sum0 = ((e00 + e01) + (e02 + e03)) + ((e04 + e05) + (e06 + e07));
        float sum1 = ((e10 + e11) + (e12 + e13)) + ((e14 + e15) + (e16 + e17));
        #pragma unroll
        for (int off = 32; off > 0; off >>= 1) {
            sum0 += __shfl_xor(sum0, off, 64);
            sum1 += __shfl_xor(sum1, off, 64);
        }
        float inv0 = 1.0f / sum0;
        float inv1 = 1.0f / sum1;

        float* orow0 = out + (size_t)(rowBase + 0) * NCELLS;
        float* orow1 = out + (size_t)(rowBase + 1) * NCELLS;
        *(float4*)(orow0 + 4 * l)       = make_float4(e00 * inv0, e01 * inv0, e02 * inv0, e03 * inv0);
        *(float4*)(orow0 + 256 + 4 * l) = make_float4(e04 * inv0, e05 * inv0, e06 * inv0, e07 * inv0);
        *(float4*)(orow1 + 4 * l)       = make_float4(e10 * inv1, e11 * inv1, e12 * inv1, e13 * inv1);
        *(float4*)(orow1 + 256 + 4 * l) = make_float4(e14 * inv1, e15 * inv1, e16 * inv1, e17 * inv1);
    }
}

extern "C" void kernel_launch(void* const* d_in, const int* in_sizes, int n_in,
                              void* d_out, int out_size, void* d_ws, size_t ws_size,
                              hipStream_t stream)
{
    const float* x  = (const float*)d_in[0];   // (8192, 64) fp32
    const float* pc = (const float*)d_in[1];   // (512, 64) fp32
    float* out = (float*)d_out;                // (8192, 512) fp32
    placecells_kernel<<<dim3(NBLOCKS), dim3(1024), LDS_BYTES, stream>>>(x, pc, out);
}